// Round 3
// baseline (137.866 us; speedup 1.0000x reference)
//
#include <hip/hip_runtime.h>

// NearestEmbed (VQ argmin + gather), MI355X gfx950.  Round 6.
// x: (B=64, D=64, H=32, W=32) fp32 ; emb: (D=64, K=512) fp32
// out0: quant (B,D,H,W) fp32 ; out1: argmin (B,H,W) as fp32.
//
// R6 (R5 post-mortem: LDS *instruction throughput* bound, not conflicts:
// 8x8 tile = 16 FMAs per ds_read_b128, pipe needs >=24 -> 1.5x oversub,
// 41 us LDS floor explains flat 70 us):
//  * 8x16 thread tile -> 21.3 FMAs/read, LDS/VALU ratio 1.5 -> 1.06.
//    LDS floor 41 -> 30.7 us.
//  * 512-thr block, ROWS=256 x CK=256, NCH=2: one block/CU (130 KB LDS),
//    8 waves/CU, x staged once, only one mid-kernel staging event.
//  * Code ownership 4ct+64j (4 strided float4s): 16B-stride reads, 2-way
//    bank aliasing = free (R5-verified, 0 conflicts).
//  * Score chain unchanged (d-ascending fmaf, fmaf(-2,acc,e2)); ascending
//    in-thread scan + index-compare merge keeps first-index tie-break.

constexpr int D    = 64;
constexpr int K    = 512;
constexpr int HW   = 1024;   // 32*32
constexpr int ROWS = 256;    // rows per block
constexpr int CK   = 256;    // codes per chunk
constexpr int NCH  = K / CK; // 2

__device__ __forceinline__ void gload16(const float* g, float* l) {
    __builtin_amdgcn_global_load_lds(
        (const __attribute__((address_space(1))) void*)g,
        (__attribute__((address_space(3))) void*)l,
        16, 0, 0);
}

__global__ __launch_bounds__(512, 1) void vq_kernel(
    const float* __restrict__ x,
    const float* __restrict__ emb,
    float* __restrict__ out_q,
    float* __restrict__ out_idx)
{
    __shared__ float xs[D][ROWS];   // 64 KB  xs[d][row]
    __shared__ float es[D][CK];     // 64 KB  es[d][code-in-chunk]
    __shared__ float e2s[K];        //  2 KB
    __shared__ int   kfin[ROWS];    //  1 KB

    const int tid = threadIdx.x;
    const int ct  = tid & 15;       // code-thread: owns codes 4ct+64j (j=0..3)
    const int rg  = tid >> 4;       // row-group 0..31: rows 4rg+r (+128 half)
    const int r0  = blockIdx.x * ROWS;
    const int b   = r0 >> 10;
    const int n0  = r0 & (HW - 1);

    const float* xg = x + ((size_t)b * D) * HW + n0;

    // ---- stage x tile (64 d x 256 rows) via global_load_lds ----
    // dest byte = li*16 (linear); one wave covers exactly one d-row (1 KB).
    #pragma unroll
    for (int p = 0; p < 8; ++p) {
        const int li = p * 512 + tid;
        const int d  = li >> 6;
        const int r4 = (li & 63) << 2;
        gload16(xg + (size_t)d * HW + r4, &xs[d][r4]);
    }
    // ---- stage emb chunk 0 (64 d x 256 codes) ----
    #pragma unroll
    for (int p = 0; p < 8; ++p) {
        const int li = p * 512 + tid;
        const int d  = li >> 6;
        const int c4 = (li & 63) << 2;
        gload16(emb + d * K + c4, &es[d][c4]);
    }

    // ---- ||e_k||^2 : one code per thread, coalesced (overlaps staging) ----
    {
        float s = 0.f;
        #pragma unroll
        for (int d = 0; d < D; ++d) {
            const float v = emb[d * K + tid];
            s = fmaf(v, v, s);
        }
        e2s[tid] = s;
    }

    float best[8];
    int   bidx[8];
    #pragma unroll
    for (int r = 0; r < 8; ++r) { best[r] = 3.4e38f; bidx[r] = 0; }

    #pragma unroll
    for (int ch = 0; ch < NCH; ++ch) {
        if (ch > 0) {
            __syncthreads();   // chunk-0 readers of es done
            #pragma unroll
            for (int p = 0; p < 8; ++p) {
                const int li = p * 512 + tid;
                const int d  = li >> 6;
                const int c4 = (li & 63) << 2;
                gload16(emb + d * K + ch * CK + c4, &es[d][c4]);
            }
        }
        __syncthreads();       // drains vmcnt: es (ch=0: also xs, e2s) visible

        float acc[8][16];
        #pragma unroll
        for (int r = 0; r < 8; ++r)
            #pragma unroll
            for (int c = 0; c < 16; ++c) acc[r][c] = 0.f;

        // hot loop: 6x ds_read_b128 (16B-stride, conflict-free) + 128 fmac
        #pragma unroll 2
        for (int d = 0; d < D; ++d) {
            const float4 xv0 = *reinterpret_cast<const float4*>(&xs[d][rg << 2]);
            const float4 xv1 = *reinterpret_cast<const float4*>(&xs[d][128 + (rg << 2)]);
            float4 ev[4];
            #pragma unroll
            for (int j = 0; j < 4; ++j)
                ev[j] = *reinterpret_cast<const float4*>(&es[d][(ct << 2) + 64 * j]);
            const float* xa = reinterpret_cast<const float*>(&xv0);
            const float* xb = reinterpret_cast<const float*>(&xv1);
            #pragma unroll
            for (int r = 0; r < 4; ++r) {
                const float x0 = xa[r];
                const float x1 = xb[r];
                #pragma unroll
                for (int j = 0; j < 4; ++j) {
                    const float* ef = reinterpret_cast<const float*>(&ev[j]);
                    #pragma unroll
                    for (int i = 0; i < 4; ++i) {
                        acc[r][j * 4 + i]     = fmaf(x0, ef[i], acc[r][j * 4 + i]);
                        acc[r + 4][j * 4 + i] = fmaf(x1, ef[i], acc[r + 4][j * 4 + i]);
                    }
                }
            }
        }

        // scoring: s = e2 - 2*acc (identical fp32 chain); per row, codes
        // scanned ascending (j,i) => strict < keeps first index.
        const int kb = ch * CK;
        float4 q[4];
        #pragma unroll
        for (int j = 0; j < 4; ++j)
            q[j] = *reinterpret_cast<const float4*>(&e2s[kb + (ct << 2) + 64 * j]);
        #pragma unroll
        for (int r = 0; r < 8; ++r) {
            #pragma unroll
            for (int j = 0; j < 4; ++j) {
                const float* qf = reinterpret_cast<const float*>(&q[j]);
                #pragma unroll
                for (int i = 0; i < 4; ++i) {
                    const float s = fmaf(-2.f, acc[r][j * 4 + i], qf[i]);
                    const int   k = kb + 64 * j + (ct << 2) + i;
                    if (s < best[r]) { best[r] = s; bidx[r] = k; }
                }
            }
        }
    }

    // ---- merge across 16 code-threads (lane bits 0..3 = ct bits) ----
    #pragma unroll
    for (int m = 1; m < 16; m <<= 1) {
        #pragma unroll
        for (int r = 0; r < 8; ++r) {
            const float ob = __shfl_xor(best[r], m, 64);
            const int   oi = __shfl_xor(bidx[r], m, 64);
            if (ob < best[r] || (ob == best[r] && oi < bidx[r])) {
                best[r] = ob; bidx[r] = oi;   // lowest index wins exact ties
            }
        }
    }

    if (ct == 0) {
        #pragma unroll
        for (int r = 0; r < 8; ++r) {
            const int rloc = (r < 4) ? ((rg << 2) + r) : (128 + (rg << 2) + (r - 4));
            kfin[rloc] = bidx[r];
            __builtin_nontemporal_store((float)bidx[r], &out_idx[r0 + rloc]);
        }
    }
    __syncthreads();

    // ---- epilogue: gather emb column, coalesced nontemporal stores ----
    const int row = tid & 255;
    const int dg  = tid >> 8;            // 2 threads/row, 32 d-planes each
    const int kq  = kfin[row];
    float* oq = out_q + ((size_t)b * D) * HW + n0 + row;
    #pragma unroll
    for (int j = 0; j < 32; ++j) {
        const int d = (dg << 5) + j;
        // emb gather per-lane scattered 4B but L1/L2-hot (128 KB table);
        // stores: consecutive rows across lanes -> full 256B lines.
        __builtin_nontemporal_store(emb[d * K + kq], &oq[(size_t)d * HW]);
    }
}

extern "C" void kernel_launch(void* const* d_in, const int* in_sizes, int n_in,
                              void* d_out, int out_size, void* d_ws, size_t ws_size,
                              hipStream_t stream)
{
    const float* x   = (const float*)d_in[0];   // 4194304 floats
    const float* emb = (const float*)d_in[1];   // 32768 floats

    float* out_q   = (float*)d_out;                     // 4194304 floats
    float* out_idx = out_q + (size_t)64 * 64 * 1024;    // 65536 floats

    // 65536 rows / 256 rows-per-block = 256 blocks of 512 threads
    // (LDS 131 KB -> 1 block/CU, 8 waves/CU)
    vq_kernel<<<256, 512, 0, stream>>>(x, emb, out_q, out_idx);
}